// Round 4
// baseline (400.559 us; speedup 1.0000x reference)
//
#include <hip/hip_runtime.h>
#include <cstdint>
#include <cstddef>

#define Bn 64
#define Hn 56
#define Wn 56
#define Cn 256
#define COn 64
#define RWn 64                              // route width = 256/4
#define XSZ ((size_t)Bn * Hn * Wn * RWn)    // 12,845,056 floats
#define NS2 28                              // 2 rows per split

__device__ __forceinline__ void f4add(float4& a, const float4& v) {
    a.x += v.x; a.y += v.y; a.z += v.z; a.w += v.w;
}
__device__ __forceinline__ float4 f4sub(const float4& a, const float4& b) {
    return make_float4(a.x - b.x, a.y - b.y, a.z - b.z, a.w - b.w);
}

// ---------------------------------------------------------------------------
// kA_w2: per-(batch, 2-row split) bin sums, register-light for deep MLP.
// S[b,kh,kw,ci] = sum over (ho,wo) of in[b, 2ho+kh, 2wo+kw, ci].
// Split s covers rows h0=2s (even) and h1=2s+1 (odd). Column parity is fixed
// per wave: even waves produce cA (kw0-set) and cB (kw2-set); odd waves
// produce R (kw1-set). Exactly one row per parity class per split, so the
// per-wave state is just 4 float4 values; the kh expansion
//   kh0 <- even row if h0<=52 (s<=26), kh2 <- even row if h0>=2 (s>=1),
//   kh1 <- odd  row if h1<=53 (s<=26); h1==55 (s==27) skipped at load
// is applied as 0/1 masks when writing the 9-bin spart slot.
// ---------------------------------------------------------------------------
__global__ __launch_bounds__(256, 4) void kA_w2(
        const float* __restrict__ in, float* __restrict__ spart) {
    const int blk   = blockIdx.x;
    const int b     = blk / NS2;
    const int split = blk - b * NS2;
    const int tid   = threadIdx.x;
    const int lane  = tid & 63;
    const int wave  = tid >> 6;

    const float* base = in + (size_t)b * (Hn * Wn * Cn) + (size_t)lane * 4
                           + (size_t)wave * Cn + (size_t)(split * 2) * (Wn * Cn);

    float4 z = make_float4(0.f, 0.f, 0.f, 0.f);
    float4 sA[2] = { z, z };   // even-wave: cA (kw0); odd-wave: R (kw1)
    float4 sB[2] = { z, z };   // even-wave: cB (kw2); odd-wave: unused

#pragma unroll
    for (int r = 0; r < 2; ++r) {
        if (r == 1 && split == NS2 - 1) continue;   // h == 55 never used
        const float* rowp = base + (size_t)r * (Wn * Cn);
        float4 R = z, e0 = z, e1 = z;
#pragma unroll
        for (int wb = 0; wb < Wn; wb += 4) {
            if (wb == 52 && wave == 3) continue;    // w == 55 never used
            const float4 v = *(const float4*)(rowp + (size_t)wb * Cn);
            if (wb == 0)  e0 = v;
            if (wb == 52) e1 = v;
            f4add(R, v);
        }
        if ((wave & 1) == 0) {
            // wave0 (w=0,4..52): cA = R;      cB = R - e0 (drop w=0)
            // wave2 (w=2,6..54): cA = R - e1; cB = R      (drop w=54)
            sA[r] = (wave == 0) ? R : f4sub(R, e1);
            sB[r] = (wave == 0) ? f4sub(R, e0) : R;
        } else {
            sA[r] = R;      // kw1 contribution (w=55 excluded at load)
        }
    }

    // cross-wave reduce + kh expansion via LDS
    __shared__ float4 lds[4][4][64];    // [wave][slot][lane], 16 KB
    lds[wave][0][lane] = sA[0];
    lds[wave][1][lane] = sB[0];
    lds[wave][2][lane] = sA[1];
    lds[wave][3][lane] = sB[1];
    __syncthreads();

    const float* f = (const float*)lds;             // [wave][slot][256]
    const int t = tid;                               // channel 0..255
#define LDSF(w, s) f[((w) * 4 + (s)) * 256 + t]
    const float evenA = LDSF(0, 0) + LDSF(2, 0);    // even row, kw0
    const float evenB = LDSF(0, 1) + LDSF(2, 1);    // even row, kw2
    const float evenO = LDSF(1, 0) + LDSF(3, 0);    // even row, kw1
    const float oddA  = LDSF(0, 2) + LDSF(2, 2);    // odd row,  kw0
    const float oddB  = LDSF(0, 3) + LDSF(2, 3);    // odd row,  kw2
    const float oddO  = LDSF(1, 2) + LDSF(3, 2);    // odd row,  kw1
#undef LDSF
    const float m0 = (split <= 26) ? 1.f : 0.f;
    const float m1 = (split <= 26) ? 1.f : 0.f;
    const float m2 = (split >= 1)  ? 1.f : 0.f;

    float* op = spart + (((size_t)b * NS2 + split) * 9) * 256 + t;
    op[0 * 256] = evenA * m0;  op[1 * 256] = evenO * m0;  op[2 * 256] = evenB * m0;
    op[3 * 256] = oddA  * m1;  op[4 * 256] = oddO  * m1;  op[5 * 256] = oddB  * m1;
    op[6 * 256] = evenA * m2;  op[7 * 256] = evenO * m2;  op[8 * 256] = evenB * m2;
}

// ---------------------------------------------------------------------------
// Fallback kA (generic NS/RPS, 9 register bins) — used only if ws is small.
// ---------------------------------------------------------------------------
__device__ __forceinline__ void f4fma(float4& a, float s, const float4& v) {
    a.x += s * v.x; a.y += s * v.y; a.z += s * v.z; a.w += s * v.w;
}
__global__ __launch_bounds__(256) void kA_bins(
        const float* __restrict__ in, float* __restrict__ spart,
        int NS, int RPS) {
    const int blk   = blockIdx.x;
    const int b     = blk / NS;
    const int split = blk - b * NS;
    const int tid   = threadIdx.x;
    const int lane  = tid & 63;
    const int wave  = tid >> 6;

    const float* base = in + (size_t)b * (Hn * Wn * Cn) + (size_t)lane * 4
                           + (size_t)wave * Cn;
    float4 acc[9];
#pragma unroll
    for (int k = 0; k < 9; ++k) acc[k] = make_float4(0.f, 0.f, 0.f, 0.f);

    const int h0 = split * RPS;
    for (int h = h0; h < h0 + RPS; ++h) {
        const bool  he  = (h & 1) == 0;
        const float rh0 = (he  && h <= 52)           ? 1.f : 0.f;
        const float rh1 = (!he && h <= 53)           ? 1.f : 0.f;
        const float rh2 = (he  && h >= 2 && h <= 54) ? 1.f : 0.f;
        if (rh0 == 0.f && rh1 == 0.f && rh2 == 0.f) continue;
        const float* rowp = base + (size_t)h * (Wn * Cn);
        float4 R  = make_float4(0.f, 0.f, 0.f, 0.f);
        float4 e0 = R, e1 = R;
#pragma unroll
        for (int wb = 0; wb < Wn; wb += 4) {
            if (wb == 52 && wave == 3) continue;
            const float4 v = *(const float4*)(rowp + (size_t)wb * Cn);
            if (wb == 0)  e0 = v;
            if (wb == 52) e1 = v;
            f4add(R, v);
        }
        const float rhE[3] = { rh0, rh1, rh2 };
        if ((wave & 1) == 0) {
            float4 cA, cB;
            if (wave == 0) { cA = R;            cB = f4sub(R, e0); }
            else           { cA = f4sub(R, e1); cB = R;            }
#pragma unroll
            for (int kh = 0; kh < 3; ++kh) {
                f4fma(acc[kh * 3 + 0], rhE[kh], cA);
                f4fma(acc[kh * 3 + 2], rhE[kh], cB);
            }
        } else {
#pragma unroll
            for (int kh = 0; kh < 3; ++kh) f4fma(acc[kh * 3 + 1], rhE[kh], R);
        }
    }

    __shared__ float4 lds4[4][9][64];
#pragma unroll
    for (int k = 0; k < 9; ++k) lds4[wave][k][lane] = acc[k];
    __syncthreads();
    const float* ldsf = (const float*)lds4;
    float* op = spart + (((size_t)b * NS + split) * 9) * 256;
#pragma unroll
    for (int k = 0; k < 9; ++k) {
        const float s = ldsf[(0 * 9 + k) * 256 + tid] + ldsf[(1 * 9 + k) * 256 + tid]
                      + ldsf[(2 * 9 + k) * 256 + tid] + ldsf[(3 * 9 + k) * 256 + tid];
        op[k * 256 + tid] = s;
    }
}

// ---------------------------------------------------------------------------
// kB: one block per batch. Reduce splits -> S[9][256], contract with conv_w,
// /729 + conv_b, dense logits, first-occurrence argmax -> route[b].
// ---------------------------------------------------------------------------
__global__ __launch_bounds__(256) void kB_logits(
        const float* __restrict__ spart,
        const float* __restrict__ convw, const float* __restrict__ convb,
        const float* __restrict__ fcw,   const float* __restrict__ fcb,
        float* __restrict__ out_logits, int* __restrict__ routes, int NS) {
    const int b = blockIdx.x;
    const int t = threadIdx.x;
    __shared__ float sS[9 * 256];
    __shared__ float pP[4][64];
    __shared__ float pld[64];
    __shared__ float lgt[4];

#pragma unroll
    for (int k = 0; k < 9; ++k) {
        float a = 0.f;
        for (int s = 0; s < NS; ++s)
            a += spart[(((size_t)b * NS + s) * 9 + k) * 256 + t];
        sS[k * 256 + t] = a;
    }
    __syncthreads();

    {
        const int co = t & 63, part = t >> 6;
        float a = 0.f;
#pragma unroll
        for (int k = 0; k < 9; ++k) {
            const int cb = part * 64;
#pragma unroll 8
            for (int ci = 0; ci < 64; ++ci)
                a += sS[k * 256 + cb + ci] * convw[(size_t)(k * 256 + cb + ci) * 64 + co];
        }
        pP[part][co] = a;
    }
    __syncthreads();

    if (t < 64)
        pld[t] = (pP[0][t] + pP[1][t] + pP[2][t] + pP[3][t]) * (1.f / 729.f) + convb[t];
    __syncthreads();

    if (t < 4) {
        float a = fcb[t];
#pragma unroll
        for (int co = 0; co < 64; ++co) a += pld[co] * fcw[co * 4 + t];
        lgt[t] = a;
        out_logits[b * 4 + t] = a;
    }
    __syncthreads();

    if (t == 0) {
        int bi = 0; float best = lgt[0];
#pragma unroll
        for (int r = 1; r < 4; ++r) if (lgt[r] > best) { best = lgt[r]; bi = r; }
        routes[b] = bi;
    }
}

// ---------------------------------------------------------------------------
// kC: routed channel-group gather. 4 float4 per thread.
// ---------------------------------------------------------------------------
__global__ __launch_bounds__(256) void kC_gather(
        const float* __restrict__ in, const int* __restrict__ routes,
        float* __restrict__ out) {
#pragma unroll
    for (int k = 0; k < 4; ++k) {
        const size_t idx = (size_t)blockIdx.x * 1024 + k * 256 + threadIdx.x;
        const size_t pix = idx >> 4;
        const int   f4i  = (int)(idx & 15);
        const int   b    = (int)(pix / (Hn * Wn));
        const int   r    = routes[b];
        const float4 v = *(const float4*)(in + pix * (size_t)Cn
                                          + (size_t)r * RWn + (size_t)f4i * 4);
        ((float4*)out)[idx] = v;
    }
}

extern "C" void kernel_launch(void* const* d_in, const int* in_sizes, int n_in,
                              void* d_out, int out_size, void* d_ws, size_t ws_size,
                              hipStream_t stream) {
    const float* in    = (const float*)d_in[0];
    const float* convw = (const float*)d_in[1];
    const float* convb = (const float*)d_in[2];
    const float* fcw   = (const float*)d_in[3];
    const float* fcb   = (const float*)d_in[4];
    float* out = (float*)d_out;

    const size_t need28 = (size_t)Bn * NS2 * 9 * 256 * sizeof(float) + 256;
    float* spart = (float*)d_ws;

    if (ws_size >= need28) {
        int* routes = (int*)((char*)d_ws + (size_t)Bn * NS2 * 9 * 256 * sizeof(float));
        kA_w2    <<<Bn * NS2, 256, 0, stream>>>(in, spart);
        kB_logits<<<Bn,       256, 0, stream>>>(spart, convw, convb, fcw, fcb,
                                                out + XSZ, routes, NS2);
        kC_gather<<<3136,     256, 0, stream>>>(in, routes, out);
    } else {
        int NS = 1;
        const int cand[5] = {14, 8, 4, 2, 1};
        for (int i = 0; i < 5; ++i) {
            const size_t need = (size_t)Bn * cand[i] * 9 * 256 * sizeof(float) + 256;
            if (ws_size >= need) { NS = cand[i]; break; }
        }
        const int RPS = Hn / NS;
        int* routes = (int*)((char*)d_ws + (size_t)Bn * NS * 9 * 256 * sizeof(float));
        kA_bins  <<<Bn * NS, 256, 0, stream>>>(in, spart, NS, RPS);
        kB_logits<<<Bn,      256, 0, stream>>>(spart, convw, convb, fcw, fcb,
                                               out + XSZ, routes, NS);
        kC_gather<<<3136,    256, 0, stream>>>(in, routes, out);
    }
}

// Round 5
// 350.609 us; speedup vs baseline: 1.1425x; 1.1425x over previous
//
#include <hip/hip_runtime.h>
#include <cstdint>
#include <cstddef>

#define Bn 64
#define Hn 56
#define Wn 56
#define Cn 256
#define RWn 64                              // route width = 256/4
#define XSZ ((size_t)Bn * Hn * Wn * RWn)    // 12,845,056 floats
#define RSTRIDE (Wn * Cn)                   // floats between rows

__device__ __forceinline__ void f4add(float4& a, const float4& v) {
    a.x += v.x; a.y += v.y; a.z += v.z; a.w += v.w;
}
__device__ __forceinline__ float4 f4sub(const float4& a, const float4& b) {
    return make_float4(a.x - b.x, a.y - b.y, a.z - b.z, a.w - b.w);
}

// ---------------------------------------------------------------------------
// kA_col: per-(batch, column) row-class sums. One WAVE per column; the load
// loop is PURE accumulate (no conditionals, no saved edges) so the compiler
// can keep many float4 loads in flight:
//   A = sum over even rows 0..54, B = sum over odd rows 1..55  (56 loads)
// then 3 cache-hit reloads give the row classes:
//   T0 (h even <=52) = A - in[54];  T2 (h even >=2) = A - in[0];
//   T1 (h odd  <=53) = B - in[55].
// V[b][w][cls][ci] <- T_cls.  (w==55 is computed but masked out in kB.)
// Grid: 64 * 14 blocks, 4 waves/block = one column per wave.
// ---------------------------------------------------------------------------
__global__ __launch_bounds__(256, 4) void kA_col(
        const float* __restrict__ in, float* __restrict__ V) {
    const int blk  = blockIdx.x;
    const int b    = blk / (Wn / 4);
    const int wg   = blk - b * (Wn / 4);
    const int lane = threadIdx.x & 63;
    const int wave = threadIdx.x >> 6;
    const int w    = wg * 4 + wave;

    const float* col = in + ((size_t)b * Hn * Wn + (size_t)w) * Cn + (size_t)lane * 4;

    float4 A = make_float4(0.f, 0.f, 0.f, 0.f);
    float4 B = make_float4(0.f, 0.f, 0.f, 0.f);
#pragma unroll
    for (int h = 0; h < Hn; h += 2) {
        f4add(A, *(const float4*)(col + (size_t)h * RSTRIDE));
        f4add(B, *(const float4*)(col + (size_t)(h + 1) * RSTRIDE));
    }
    const float4 r0  = *(const float4*)(col);
    const float4 r54 = *(const float4*)(col + (size_t)54 * RSTRIDE);
    const float4 r55 = *(const float4*)(col + (size_t)55 * RSTRIDE);

    const float4 T0 = f4sub(A, r54);
    const float4 T2 = f4sub(A, r0);
    const float4 T1 = f4sub(B, r55);

    float4* op = (float4*)(V + (((size_t)b * Wn + w) * 3) * 256) + lane;
    op[0]       = T0;      // cls 0, 1KB coalesced per wave
    op[64]      = T1;      // cls 1
    op[128]     = T2;      // cls 2
}

// ---------------------------------------------------------------------------
// kB: one block per batch. Fold columns into S[9][256] with the same
// even/odd-minus-edges trick, then contract with conv_w, /729 + conv_b,
// dense logits, first-occurrence argmax -> routes[b].
// Column classes: kw0 = even w<=52 (evenSum - T[54]); kw2 = even 2..54
// (evenSum - T[0]); kw1 = odd w<=53 (oddSum - T[55]).
// ---------------------------------------------------------------------------
__global__ __launch_bounds__(256) void kB_logits(
        const float* __restrict__ V,
        const float* __restrict__ convw, const float* __restrict__ convb,
        const float* __restrict__ fcw,   const float* __restrict__ fcb,
        float* __restrict__ out_logits, int* __restrict__ routes) {
    const int b = blockIdx.x;
    const int t = threadIdx.x;
    __shared__ float sS[9 * 256];
    __shared__ float pP[4][64];
    __shared__ float pld[64];
    __shared__ float lgt[4];

    const float* Vb = V + (size_t)b * Wn * 3 * 256;
    float Ae[3] = {0.f, 0.f, 0.f};   // even-w sums per row-class
    float Bo[3] = {0.f, 0.f, 0.f};   // odd-w sums per row-class
#pragma unroll
    for (int w = 0; w < Wn; w += 2) {
#pragma unroll
        for (int kh = 0; kh < 3; ++kh) {
            Ae[kh] += Vb[((w    ) * 3 + kh) * 256 + t];
            Bo[kh] += Vb[((w + 1) * 3 + kh) * 256 + t];
        }
    }
#pragma unroll
    for (int kh = 0; kh < 3; ++kh) {
        const float t0  = Vb[(0  * 3 + kh) * 256 + t];
        const float t54 = Vb[(54 * 3 + kh) * 256 + t];
        const float t55 = Vb[(55 * 3 + kh) * 256 + t];
        sS[(kh * 3 + 0) * 256 + t] = Ae[kh] - t54;
        sS[(kh * 3 + 1) * 256 + t] = Bo[kh] - t55;
        sS[(kh * 3 + 2) * 256 + t] = Ae[kh] - t0;
    }
    __syncthreads();

    // contraction: part = t>>6 handles 64 input channels, co = t&63
    {
        const int co = t & 63, part = t >> 6;
        float a = 0.f;
#pragma unroll
        for (int k = 0; k < 9; ++k) {
            const int cb = part * 64;
#pragma unroll 8
            for (int ci = 0; ci < 64; ++ci)
                a += sS[k * 256 + cb + ci] * convw[(size_t)(k * 256 + cb + ci) * 64 + co];
        }
        pP[part][co] = a;
    }
    __syncthreads();

    if (t < 64)
        pld[t] = (pP[0][t] + pP[1][t] + pP[2][t] + pP[3][t]) * (1.f / 729.f) + convb[t];
    __syncthreads();

    if (t < 4) {
        float a = fcb[t];
#pragma unroll
        for (int co = 0; co < 64; ++co) a += pld[co] * fcw[co * 4 + t];
        lgt[t] = a;
        out_logits[b * 4 + t] = a;
    }
    __syncthreads();

    if (t == 0) {
        int bi = 0; float best = lgt[0];
#pragma unroll
        for (int r = 1; r < 4; ++r) if (lgt[r] > best) { best = lgt[r]; bi = r; }
        routes[b] = bi;
    }
}

// ---------------------------------------------------------------------------
// kC: routed channel-group gather. One float4 per thread (R2's best config).
// total float4 = 64*56*56*16 = 3,211,264 = 12544 blocks * 256 threads.
// ---------------------------------------------------------------------------
__global__ __launch_bounds__(256) void kC_gather(
        const float* __restrict__ in, const int* __restrict__ routes,
        float* __restrict__ out) {
    const size_t idx = (size_t)blockIdx.x * 256 + threadIdx.x;  // float4 index
    const size_t pix = idx >> 4;
    const int   f4i  = (int)(idx & 15);
    const int   b    = (int)(pix / (Hn * Wn));
    const int   r    = routes[b];
    const float4 v = *(const float4*)(in + pix * (size_t)Cn
                                      + (size_t)r * RWn + (size_t)f4i * 4);
    ((float4*)out)[idx] = v;
}

extern "C" void kernel_launch(void* const* d_in, const int* in_sizes, int n_in,
                              void* d_out, int out_size, void* d_ws, size_t ws_size,
                              hipStream_t stream) {
    const float* in    = (const float*)d_in[0];
    const float* convw = (const float*)d_in[1];
    const float* convb = (const float*)d_in[2];
    const float* fcw   = (const float*)d_in[3];
    const float* fcb   = (const float*)d_in[4];
    float* out = (float*)d_out;

    const size_t vBytes = (size_t)Bn * Wn * 3 * 256 * sizeof(float);  // 11 MB
    float* V      = (float*)d_ws;
    int*   routes = (int*)((char*)d_ws + vBytes);

    kA_col   <<<Bn * (Wn / 4), 256, 0, stream>>>(in, V);
    kB_logits<<<Bn,            256, 0, stream>>>(V, convw, convb, fcw, fcb,
                                                 out + XSZ, routes);
    kC_gather<<<12544,         256, 0, stream>>>(in, routes, out);
}